// Round 1
// 405.223 us; speedup vs baseline: 1.0455x; 1.0455x over previous
//
#include <hip/hip_runtime.h>
#include <hip/hip_bf16.h>
#include <stdint.h>

// Problem constants (B=4, S=2048, IN=4096, OUT=4096, FP=256)
// Harness dtype contract (verified R3): reference float16 tensors are
// delivered/read as FLOAT32; int8 -> int32; output read as float32.
#define N_TOK 8192
#define IN_F  4096
#define OUT_F 4096
#define FP_F  256
#define INT_F 3840
#define PROW  1920    // packed int4 bytes per row (INT_F/2)

typedef int    v4i   __attribute__((ext_vector_type(4)));
typedef int    v16i  __attribute__((ext_vector_type(16)));
typedef float  v16f  __attribute__((ext_vector_type(16)));
typedef __bf16 bf16x8 __attribute__((ext_vector_type(8)));

// ---------------- workspace layout (bytes) ----------------
#define WS_QP   0u            // [N_TOK][PROW] packed codes c=q+8, PRE-SWIZZLED
#define WS_WP   15728640u     // [OUT_F][PROW] packed codes w+8, PRE-SWIZZLED
#define WS_FPX  23592960u     // [N_TOK][FP_F] bf16 outliers, PRE-SWIZZLED
#define WS_WFP  27787264u     // [OUT_F][FP_F] bf16 fp_weight, PRE-SWIZZLED
#define WS_F1   29884416u     // [N_TOK] float: scale
#define WS_F2   29917184u     // [N_TOK] float: -8*sumc*scale
#define WS_F3   29949952u     // [N_TOK] float: row min
#define WS_NEED 29982720u

// Group-16 nibble packing (both q and w): group g = 16 codes c[0..15];
// byte j (j<8) = c[j] | (c[j+8]<<4). One 8B slot = one 16-code MFMA fragment.
// Biased-code algebra (verified passing): D = sum (q+8)(w+8);
// out = (D*sc + f2)*ws + f3*rw + bias + bf16_outlier_dot.
//
// SWIZZLE IS BAKED INTO THE WORKSPACE (guide rule #21: gload_lds writes
// lane-linear, so the source must carry the inverse permutation):
//   int rows (64B, 8 slots of 8B):   phys8  = s8  ^ ((row>>1)&7)
//   bf16 rows (64B/round, 4 x 16B):  phys16 = s16 ^ ((row>>1)&3)
// row-in-tile == global row mod 128, and both swizzles use only bits 1..3 /
// 1..2 of the row, so one baked layout serves every 128-aligned tile.

__global__ __launch_bounds__(256) void zero_out_kernel(uint4* __restrict__ o) {
  o[(size_t)blockIdx.x * 256 + threadIdx.x] = uint4{0, 0, 0, 0};
}

// ---------------- fused prep kernel ----------------
// grid = [0,8192): quant tokens | [8192,15872): pack_w | [15872,16896): conv_wfp
__global__ __launch_bounds__(256) void prep_kernel(
    const float* __restrict__ x,
    const int* __restrict__ int_idx, const int* __restrict__ fp_idx,
    const int* __restrict__ int_w, const float* __restrict__ fp_w,
    uint8_t* __restrict__ qp, uint8_t* __restrict__ wp,
    __hip_bfloat16* __restrict__ fpx, __hip_bfloat16* __restrict__ wfp,
    float* __restrict__ f1, float* __restrict__ f2, float* __restrict__ f3) {
  __shared__ uint2 qb[240];               // 1920B packed output staging
  __shared__ float smn[4], smx[4], ssum[4];
  __shared__ float s_mn, s_inv, s_sc;

  int tid = threadIdx.x;
  int blk = blockIdx.x;

  if (blk >= N_TOK) {
    int pb = blk - N_TOK;
    if (pb < OUT_F * 480 / 256) {
      // ---- pack_w: int32 weights -> biased nibbles, swizzled dest ----
      int t = pb * 256 + tid;
      int r = t / 480, u = t % 480;
      int g = u >> 1, h = u & 1;
      const int* src = int_w + (size_t)r * INT_F + g * 16 + h * 4;
      int4 lo = *(const int4*)src;
      int4 hi = *(const int4*)(src + 8);
      uint32_t o = (uint32_t)((lo.x + 8) & 15) | (uint32_t)((hi.x + 8) & 15) << 4 |
                   (uint32_t)((lo.y + 8) & 15) << 8 | (uint32_t)((hi.y + 8) & 15) << 12 |
                   (uint32_t)((lo.z + 8) & 15) << 16 | (uint32_t)((hi.z + 8) & 15) << 20 |
                   (uint32_t)((lo.w + 8) & 15) << 24 | (uint32_t)((hi.w + 8) & 15) << 28;
      int gs = (g & ~7) | ((g & 7) ^ ((r >> 1) & 7));            // baked int swizzle
      ((uint32_t*)wp)[(size_t)r * 480 + gs * 2 + h] = o;
    } else {
      // ---- conv_wfp: fp_weight f32 -> bf16, swizzled dest ----
      int t = (pb - OUT_F * 480 / 256) * 256 + tid;
      int i = t * 4;
      int r = i >> 8, c = i & 255;
      float4 v = *(const float4*)(fp_w + i);
      __hip_bfloat16 b[4] = {__float2bfloat16(v.x), __float2bfloat16(v.y),
                             __float2bfloat16(v.z), __float2bfloat16(v.w)};
      int cs = (c & ~0x18) | (((((c) >> 3) & 3) ^ ((r >> 1) & 3)) << 3);  // baked bf16 swizzle
      *(uint2*)(wfp + (size_t)r * 256 + cs) = *(const uint2*)b;
    }
    return;
  }

  // ---- quant: one block per token, values in 15 registers ----
  int n = blk;
  const float* xr = x + (size_t)n * IN_F;

  float v[15];
  float lmn = 1e30f, lmx = -1e30f;
#pragma unroll
  for (int k = 0; k < 15; k++) {
    v[k] = xr[int_idx[tid + 256 * k]];
    lmn = fminf(lmn, v[k]);
    lmx = fmaxf(lmx, v[k]);
  }
  // fp outlier gather (independent, overlaps reduction); baked bf16 swizzle
  {
    int sw2 = (n >> 1) & 3;
    int cs = (tid & ~0x18) | ((((tid >> 3) & 3) ^ sw2) << 3);
    fpx[(size_t)n * FP_F + cs] = __float2bfloat16(xr[fp_idx[tid]]);
  }

#pragma unroll
  for (int off = 32; off > 0; off >>= 1) {
    lmn = fminf(lmn, __shfl_xor(lmn, off, 64));
    lmx = fmaxf(lmx, __shfl_xor(lmx, off, 64));
  }
  int wv = tid >> 6, ln = tid & 63;
  if (ln == 0) { smn[wv] = lmn; smx[wv] = lmx; }
  __syncthreads();
  if (tid == 0) {
    float mn = fminf(fminf(smn[0], smn[1]), fminf(smn[2], smn[3]));
    float mx = fmaxf(fmaxf(smx[0], smx[1]), fmaxf(smx[2], smx[3]));
    float sc = fmaxf((mx - mn) / 15.0f, 1e-8f);   // IEEE f32 div, matches ref
    s_mn = mn; s_sc = sc; s_inv = 1.0f / sc;
    f1[n] = sc; f3[n] = mn;
  }
  __syncthreads();
  float mn = s_mn, inv = s_inv;

  uint8_t* qbb = (uint8_t*)qb;
  int swq = (n >> 1) & 7;                 // baked int swizzle (uniform per block)
  float lsum = 0.0f;
#pragma unroll
  for (int k = 0; k < 15; k++) {
    // value index i = tid + 256k; code c in [0,15]
    float c = fminf(fmaxf(rintf((v[k] - mn) * inv), 0.0f), 15.0f);
    lsum += c;
    float ch = __shfl_down(c, 8, 64);      // partner value i+8 (same wave)
    if ((tid & 15) < 8) {                  // low-nibble owner writes byte
      int G = (tid >> 4) + 16 * k;
      int pos = ((G & ~7) | ((G & 7) ^ swq)) * 8 + (tid & 7);
      qbb[pos] = (uint8_t)((uint32_t)c | ((uint32_t)ch << 4));
    }
  }
#pragma unroll
  for (int off = 32; off > 0; off >>= 1) lsum += __shfl_xor(lsum, off, 64);
  if (ln == 0) ssum[wv] = lsum;
  __syncthreads();
  if (tid == 0)
    f2[n] = -8.0f * (ssum[0] + ssum[1] + ssum[2] + ssum[3]) * s_sc;
  if (tid < 240)
    *(uint2*)(qp + (size_t)n * PROW + tid * 8) = qb[tid];
}

__device__ inline v4i unpack_nib(uint2 u) {
  v4i r;
  r[0] = (int)(u.x & 0x0F0F0F0Fu);
  r[1] = (int)(u.y & 0x0F0F0F0Fu);
  r[2] = (int)((u.x >> 4) & 0x0F0F0F0Fu);
  r[3] = (int)((u.y >> 4) & 0x0F0F0F0Fu);
  return r;
}

__device__ __forceinline__ void gl16(const void* g, void* l) {
  __builtin_amdgcn_global_load_lds(
      (const __attribute__((address_space(1))) void*)g,
      (__attribute__((address_space(3))) void*)l, 16, 0, 0);
}

// Kernel 3 v4: 128x128 block, 4 waves (2x2 quadrants of 64x64, each 2x2
// 32-tiles). Staging via global_load_lds dwordx4 into LINEAR LDS (swizzle
// pre-baked in workspace), true LDS double-buffer (2 x 16KB), counted
// s_waitcnt vmcnt(4) so prefetch loads stay in flight across barriers.
// Int phase: 30 kt of K=128 (A 8KB + B 8KB per buffer).
// bf16 phase: 8 rounds of K=32, same dbuf structure; round 0 staged before
// the dequant fold so its latency hides under the fold's VALU work.
__global__ __launch_bounds__(256, 4) void gemm_kernel(
    const uint8_t* __restrict__ qp, const uint8_t* __restrict__ wp,
    const __hip_bfloat16* __restrict__ fpx, const __hip_bfloat16* __restrict__ wfp,
    const float* __restrict__ f1, const float* __restrict__ f2,
    const float* __restrict__ f3,
    const float* __restrict__ wscale, const float* __restrict__ reduced,
    const float* __restrict__ bias, float* __restrict__ out) {
  __shared__ int4 lds4[2048];             // 32 KB = 2 buffers x (A 8K + B 8K)
  int8_t* lds = (int8_t*)lds4;

  int tid = threadIdx.x;
  int wave = tid >> 6, lane = tid & 63;
  int wm = wave >> 1, wn = wave & 1;
  int blk = blockIdx.x;
  int tileM = ((blk & 7) << 3) | ((blk >> 3) & 7);   // XCD-aware swizzle
  int tileN = blk >> 6;
  int n0 = tileM * 128, o0 = tileN * 128;

  union { v16i i; v16f f; } acc[2][2];
#pragma unroll
  for (int mi = 0; mi < 2; mi++)
#pragma unroll
    for (int ni = 0; ni < 2; ni++)
#pragma unroll
      for (int e = 0; e < 16; e++) acc[mi][ni].i[e] = 0;

  int m = lane & 31, kg = lane >> 5;

  // staging: thread covers 16B chunks c = tid and tid+256; chunk c maps to
  // LDS byte c*16 (lane-linear, required by global_load_lds) = row*64 + q*16
  int row0 = tid >> 2, q16 = (tid & 3) * 16;
  int l0 = tid * 16, l1 = 4096 + tid * 16;
  const uint8_t* gA0 = qp + (size_t)(n0 + row0) * PROW + q16;
  const uint8_t* gA1 = qp + (size_t)(n0 + 64 + row0) * PROW + q16;
  const uint8_t* gB0 = wp + (size_t)(o0 + row0) * PROW + q16;
  const uint8_t* gB1 = wp + (size_t)(o0 + 64 + row0) * PROW + q16;

#define STAGE_INT(buf, kt) do {                                  \
    gl16(gA0 + (kt) * 64, lds + (buf) * 16384 + l0);             \
    gl16(gA1 + (kt) * 64, lds + (buf) * 16384 + l1);             \
    gl16(gB0 + (kt) * 64, lds + (buf) * 16384 + 8192 + l0);      \
    gl16(gB1 + (kt) * 64, lds + (buf) * 16384 + 8192 + l1);      \
  } while (0)

  auto compute_int = [&](const int8_t* lb) {
#pragma unroll
    for (int ks = 0; ks < 4; ks++) {
      int s8 = ks * 2 + kg;
      v4i a[2], b[2];
#pragma unroll
      for (int mi = 0; mi < 2; mi++) {
        int row = wm * 64 + mi * 32 + m;
        a[mi] = unpack_nib(*(const uint2*)&lb[row * 64 + ((s8 ^ ((row >> 1) & 7)) * 8)]);
      }
#pragma unroll
      for (int ni = 0; ni < 2; ni++) {
        int row = wn * 64 + ni * 32 + m;
        b[ni] = unpack_nib(*(const uint2*)&lb[8192 + row * 64 + ((s8 ^ ((row >> 1) & 7)) * 8)]);
      }
#pragma unroll
      for (int mi = 0; mi < 2; mi++)
#pragma unroll
        for (int ni = 0; ni < 2; ni++)
          acc[mi][ni].i = __builtin_amdgcn_mfma_i32_32x32x32_i8(
              a[mi], b[ni], acc[mi][ni].i, 0, 0, 0);
    }
  };

  // ---------------- int4 phase: 30 k-tiles of K=128, dbuf ----------------
  STAGE_INT(0, 0);
#pragma unroll 1
  for (int kt = 0; kt < 30; kt += 2) {
    STAGE_INT(1, kt + 1);
    asm volatile("s_waitcnt vmcnt(4)" ::: "memory");   // buf0's 4 loads done
    __builtin_amdgcn_s_barrier();
    compute_int(lds);
    __builtin_amdgcn_s_barrier();
    if (kt + 2 < 30) {
      STAGE_INT(0, kt + 2);
      asm volatile("s_waitcnt vmcnt(4)" ::: "memory"); // buf1's 4 loads done
    } else {
      asm volatile("s_waitcnt vmcnt(0)" ::: "memory");
    }
    __builtin_amdgcn_s_barrier();
    compute_int(lds + 16384);
    __builtin_amdgcn_s_barrier();
  }

  // bf16 staging pointers (row stride 512B; kr selects 64B k-chunk)
  const uint8_t* fxb = (const uint8_t*)fpx;
  const uint8_t* fwb = (const uint8_t*)wfp;
  const uint8_t* gFA0 = fxb + (size_t)(n0 + row0) * 512 + q16;
  const uint8_t* gFA1 = fxb + (size_t)(n0 + 64 + row0) * 512 + q16;
  const uint8_t* gFB0 = fwb + (size_t)(o0 + row0) * 512 + q16;
  const uint8_t* gFB1 = fwb + (size_t)(o0 + 64 + row0) * 512 + q16;

#define STAGE_BF(buf, kr) do {                                   \
    gl16(gFA0 + (kr) * 64, lds + (buf) * 16384 + l0);            \
    gl16(gFA1 + (kr) * 64, lds + (buf) * 16384 + l1);            \
    gl16(gFB0 + (kr) * 64, lds + (buf) * 16384 + 8192 + l0);     \
    gl16(gFB1 + (kr) * 64, lds + (buf) * 16384 + 8192 + l1);     \
  } while (0)

  // stage bf16 round 0 now; latency hides under the dequant fold below
  STAGE_BF(0, 0);

  // -------- in-place dequant fold: acc.i -> acc.f (exact, D < 2^24) --------
  int col = lane & 31, rb4 = (lane >> 5) * 4;
  float cws[2], crw[2], cbs[2];
#pragma unroll
  for (int ni = 0; ni < 2; ni++) {
    int o = o0 + wn * 64 + ni * 32 + col;
    cws[ni] = wscale[o]; crw[ni] = reduced[o]; cbs[ni] = bias[o];
  }
#pragma unroll
  for (int mi = 0; mi < 2; mi++) {
#pragma unroll
    for (int reg = 0; reg < 16; reg++) {
      int row = (reg & 3) + 8 * (reg >> 2) + rb4;
      int n = n0 + wm * 64 + mi * 32 + row;
      float a1 = f1[n], a2 = f2[n], a3 = f3[n];
      float d0 = (float)acc[mi][0].i[reg];
      float d1 = (float)acc[mi][1].i[reg];
      acc[mi][0].f[reg] = (d0 * a1 + a2) * cws[0] + a3 * crw[0] + cbs[0];
      acc[mi][1].f[reg] = (d1 * a1 + a2) * cws[1] + a3 * crw[1] + cbs[1];
    }
  }

  auto compute_bf = [&](const int8_t* lb) {
#pragma unroll
    for (int kstep = 0; kstep < 2; kstep++) {
      int s16 = kstep * 2 + kg;
      bf16x8 a[2], b[2];
#pragma unroll
      for (int mi = 0; mi < 2; mi++) {
        int row = wm * 64 + mi * 32 + m;
        a[mi] = *(const bf16x8*)&lb[row * 64 + ((s16 ^ ((row >> 1) & 3)) * 16)];
      }
#pragma unroll
      for (int ni = 0; ni < 2; ni++) {
        int row = wn * 64 + ni * 32 + m;
        b[ni] = *(const bf16x8*)&lb[8192 + row * 64 + ((s16 ^ ((row >> 1) & 3)) * 16)];
      }
#pragma unroll
      for (int mi = 0; mi < 2; mi++)
#pragma unroll
        for (int ni = 0; ni < 2; ni++)
          acc[mi][ni].f = __builtin_amdgcn_mfma_f32_32x32x16_bf16(
              a[mi], b[ni], acc[mi][ni].f, 0, 0, 0);
    }
  };

  // ---------------- bf16 outlier phase: 8 rounds of K=32, dbuf ----------------
#pragma unroll 1
  for (int kr = 0; kr < 8; kr += 2) {
    STAGE_BF(1, kr + 1);
    asm volatile("s_waitcnt vmcnt(4)" ::: "memory");
    __builtin_amdgcn_s_barrier();
    compute_bf(lds);
    __builtin_amdgcn_s_barrier();
    if (kr + 2 < 8) {
      STAGE_BF(0, kr + 2);
      asm volatile("s_waitcnt vmcnt(4)" ::: "memory");
    } else {
      asm volatile("s_waitcnt vmcnt(0)" ::: "memory");
    }
    __builtin_amdgcn_s_barrier();
    compute_bf(lds + 16384);
    __builtin_amdgcn_s_barrier();
  }

  // ---------------- store (f32) ----------------
#pragma unroll
  for (int mi = 0; mi < 2; mi++) {
#pragma unroll
    for (int ni = 0; ni < 2; ni++) {
      int o = o0 + wn * 64 + ni * 32 + col;
#pragma unroll
      for (int reg = 0; reg < 16; reg++) {
        int row = (reg & 3) + 8 * (reg >> 2) + rb4;
        int n = n0 + wm * 64 + mi * 32 + row;
        out[(size_t)n * OUT_F + o] = acc[mi][ni].f[reg];
      }
    }
  }
#undef STAGE_INT
#undef STAGE_BF
}

extern "C" void kernel_launch(void* const* d_in, const int* in_sizes, int n_in,
                              void* d_out, int out_size, void* d_ws, size_t ws_size,
                              hipStream_t stream) {
  const float* x     = (const float*)d_in[0];
  const int*   int_w = (const int*)d_in[1];
  const float* fp_w  = (const float*)d_in[2];
  const float* bias  = (const float*)d_in[3];
  const float* wsc   = (const float*)d_in[4];
  const float* red   = (const float*)d_in[5];
  const int*   iidx  = (const int*)d_in[6];
  const int*   fidx  = (const int*)d_in[7];
  float*       out   = (float*)d_out;

  if (ws_size < (size_t)WS_NEED) {
    zero_out_kernel<<<out_size / 1024, 256, 0, stream>>>((uint4*)d_out);
    return;
  }

  uint8_t* ws = (uint8_t*)d_ws;
  uint8_t*        qp  = ws + WS_QP;
  uint8_t*        wpk = ws + WS_WP;
  __hip_bfloat16* fpx = (__hip_bfloat16*)(ws + WS_FPX);
  __hip_bfloat16* wfp = (__hip_bfloat16*)(ws + WS_WFP);
  float*          f1  = (float*)(ws + WS_F1);
  float*          f2  = (float*)(ws + WS_F2);
  float*          f3  = (float*)(ws + WS_F3);

  // fused prep: quant (8192) | pack_w (7680) | conv_wfp (1024)
  prep_kernel<<<N_TOK + OUT_F * 480 / 256 + OUT_F * FP_F / 4 / 256, 256, 0, stream>>>(
      x, iidx, fidx, int_w, fp_w, qp, wpk, fpx, wfp, f1, f2, f3);
  gemm_kernel<<<(N_TOK / 128) * (OUT_F / 128), 256, 0, stream>>>(
      qp, wpk, fpx, wfp, f1, f2, f3, wsc, red, bias, out);
}